// Round 3
// baseline (185.109 us; speedup 1.0000x reference)
//
#include <hip/hip_runtime.h>
#include <math.h>

typedef __attribute__((ext_vector_type(4))) float f32x4;
typedef __attribute__((ext_vector_type(8))) short s16x8;
typedef __attribute__((ext_vector_type(4))) short s16x4;
typedef __attribute__((ext_vector_type(4))) unsigned int u32x4;

#define NB 4
#define CH 128
#define ICH 64
#define NSP 4096
#define KSPLIT 16
#define SEGK (NSP / KSPLIT)   // 256
#define LDK 72    // LDS row stride (bf16): 144 B, 16B-aligned, 2-way banks only
#define LDW 136   // k_proj W LDS stride

static __device__ __forceinline__ unsigned short f2bf(float f) {
  unsigned int u = __builtin_bit_cast(unsigned int, f);
  u += 0x7fffu + ((u >> 16) & 1u);   // RNE
  return (unsigned short)(u >> 16);
}

// ---------------- Kernel 1: one projection per block (MFMA) ------------------
// z=0: thetaT [B][N][IC] (pre-scaled by log2e); z=1: phiT [B][N][IC]; z=2: g [B][IC][N]
__global__ __launch_bounds__(256) void k_proj(
    const float* __restrict__ x,
    const float* __restrict__ gw, const float* __restrict__ gbias,
    const float* __restrict__ tw, const float* __restrict__ tbias,
    const float* __restrict__ pw, const float* __restrict__ pbias,
    unsigned short* __restrict__ thetaT, unsigned short* __restrict__ phiT,
    unsigned short* __restrict__ gout)
{
  __shared__ __align__(16) float sxf[CH * 65];
  __shared__ __align__(16) unsigned short sW[ICH * LDW];
  const int b = blockIdx.y, z = blockIdx.z;
  const int n0 = blockIdx.x * 64;
  const int t = threadIdx.x;
  const float* Wz = (z == 0) ? tw : (z == 1) ? pw : gw;
  const float* Bz = (z == 0) ? tbias : (z == 1) ? pbias : gbias;
  const float scl = (z == 0) ? 1.44269504f : 1.0f;   // fold log2(e) into theta
  const float* xb = x + (size_t)b * CH * NSP;
#pragma unroll
  for (int i = 0; i < 8; ++i) {
    int idx = t + 256 * i;
    int c = idx >> 4, ch = idx & 15;
    *(float4*)(sxf + c * 65 + ch * 4) = *(const float4*)(xb + (size_t)c * NSP + n0 + ch * 4);
  }
#pragma unroll
  for (int i = 0; i < 8; ++i) {
    int idx = t + 256 * i;
    int o = idx >> 5, col = (idx & 31) * 4;
    float4 wv = *(const float4*)(Wz + o * CH + col);
    unsigned int p0 = (unsigned int)f2bf(wv.x) | ((unsigned int)f2bf(wv.y) << 16);
    unsigned int p1 = (unsigned int)f2bf(wv.z) | ((unsigned int)f2bf(wv.w) << 16);
    *(unsigned int*)(&sW[o * LDW + col]) = p0;
    *(unsigned int*)(&sW[o * LDW + col + 2]) = p1;
  }
  __syncthreads();

  const int wave = t >> 6, lane = t & 63;
  const int l15 = lane & 15, quad = lane >> 4;
  const int nw = wave * 16;
  s16x8 aq[4];
#pragma unroll
  for (int kc = 0; kc < 4; ++kc) {
#pragma unroll
    for (int j = 0; j < 8; ++j)
      aq[kc][j] = (short)f2bf(sxf[(kc * 32 + quad * 8 + j) * 65 + nw + l15]);
  }
  __syncthreads();

  unsigned short* ldsT = (unsigned short*)sxf;  // g transpose buffer [n][o] stride LDK

#pragma unroll
  for (int osub = 0; osub < 4; ++osub) {
    f32x4 acc = (f32x4){0.f, 0.f, 0.f, 0.f};
#pragma unroll
    for (int kc = 0; kc < 4; ++kc) {
      const unsigned short* wp = &sW[(osub * 16 + l15) * LDW + kc * 32 + quad * 8];
      s16x4 lo = *(const s16x4*)(wp);
      s16x4 hi = *(const s16x4*)(wp + 4);
      s16x8 bw = __builtin_shufflevector(lo, hi, 0, 1, 2, 3, 4, 5, 6, 7);
      acc = __builtin_amdgcn_mfma_f32_16x16x32_bf16(aq[kc], bw, acc, 0, 0, 0);
    }
    float bv = Bz[osub * 16 + l15];
    if (z < 2) {
      unsigned short* outp = (z == 0) ? thetaT : phiT;
#pragma unroll
      for (int r = 0; r < 4; ++r)
        outp[((size_t)b * NSP + n0 + nw + quad * 4 + r) * ICH + osub * 16 + l15] =
            f2bf((acc[r] + bv) * scl);
    } else {
#pragma unroll
      for (int r = 0; r < 4; ++r)
        ldsT[(nw + quad * 4 + r) * LDK + osub * 16 + l15] = f2bf(acc[r] + bv);
    }
  }
  if (z == 2) {
    __syncthreads();
    int o = t >> 2, chunk = t & 3;
    unsigned short vv[16];
#pragma unroll
    for (int jj = 0; jj < 16; ++jj) vv[jj] = ldsT[(chunk * 16 + jj) * LDK + o];
    unsigned int words[8];
#pragma unroll
    for (int i = 0; i < 8; ++i)
      words[i] = (unsigned int)vv[2 * i] | ((unsigned int)vv[2 * i + 1] << 16);
    unsigned short* gp = gout + ((size_t)b * ICH + o) * NSP + n0 + chunk * 16;
    *(u32x4*)(gp) = (u32x4){words[0], words[1], words[2], words[3]};
    *(u32x4*)(gp + 8) = (u32x4){words[4], words[5], words[6], words[7]};
  }
}

// ---------------- Kernel 2: flash attention partials -------------------------
// 4 waves/block, q-tile 256 (64 q/wave), K-tile 64, K-split 16.
// exp2 path (theta pre-scaled); trunc bf16 P; row-sum l via ones-column MFMA.
__global__ __launch_bounds__(256, 3) void k_attn(
    const unsigned short* __restrict__ thetaT,
    const unsigned short* __restrict__ phiT,
    const unsigned short* __restrict__ gmat,
    unsigned short* __restrict__ Opart, float* __restrict__ lpart)
{
  __shared__ unsigned short ldsK[64 * LDK];
  __shared__ unsigned short ldsV[64 * LDK];
  __shared__ unsigned short ldsP[4][16 * LDK];   // per-wave 16-row P buffer
  const int qt = blockIdx.x, b = blockIdx.y, seg = blockIdx.z;
  const int t = threadIdx.x;
  const int wave = t >> 6, lane = t & 63;
  const int l15 = lane & 15, quad = lane >> 4;
  const int q0 = qt * 256 + wave * 64;

  s16x8 aq[4][2];
  const unsigned short* th = thetaT + ((size_t)b * NSP + q0) * ICH;
#pragma unroll
  for (int qs = 0; qs < 4; ++qs)
#pragma unroll
    for (int ks = 0; ks < 2; ++ks)
      aq[qs][ks] = __builtin_bit_cast(s16x8,
          *(const u32x4*)(th + (qs * 16 + l15) * ICH + ks * 32 + quad * 8));

  f32x4 Oacc[4][4];
  f32x4 lacc[4];
#pragma unroll
  for (int i = 0; i < 4; ++i) {
    lacc[i] = (f32x4){0.f, 0.f, 0.f, 0.f};
#pragma unroll
    for (int j = 0; j < 4; ++j) Oacc[i][j] = (f32x4){0.f, 0.f, 0.f, 0.f};
  }

  // ones-column B-frag: B[k][n]=(n==0); lane n=l15 -> l15==0 holds bf16 1.0
  s16x8 bones;
  {
    short v = (l15 == 0) ? (short)0x3F80 : (short)0;
#pragma unroll
    for (int j = 0; j < 8; ++j) bones[j] = v;
  }

  const unsigned short* ph = phiT + (size_t)b * NSP * ICH;
  const unsigned short* gb = gmat + (size_t)b * ICH * NSP;
  const int k0 = seg * SEGK;

  for (int kt = 0; kt < SEGK / 64; ++kt) {
    const int key0 = k0 + kt * 64;
    __syncthreads();
    // stage K[key][d] and V^T[d][key]; 1024 16B chunks over 256 threads
#pragma unroll
    for (int i = 0; i < 4; ++i) {
      int idx = t + 256 * i;
      int rr = (idx >> 3) & 63, c8 = (idx & 7) * 8;
      if (idx < 512)
        *(u32x4*)(&ldsK[rr * LDK + c8]) =
            *(const u32x4*)(ph + (size_t)(key0 + rr) * ICH + c8);
      else
        *(u32x4*)(&ldsV[rr * LDK + c8]) =
            *(const u32x4*)(gb + (size_t)rr * NSP + key0 + c8);
    }
    __syncthreads();

    s16x8 bk[4][2];
#pragma unroll
    for (int kc = 0; kc < 4; ++kc)
#pragma unroll
      for (int ks = 0; ks < 2; ++ks)
        bk[kc][ks] = *(const s16x8*)(&ldsK[(kc * 16 + l15) * LDK + ks * 32 + quad * 8]);
    s16x8 bv[2][4];
#pragma unroll
    for (int ks = 0; ks < 2; ++ks)
#pragma unroll
      for (int ds = 0; ds < 4; ++ds)
        bv[ks][ds] = *(const s16x8*)(&ldsV[(ds * 16 + l15) * LDK + ks * 32 + quad * 8]);

    unsigned short* myP = &ldsP[wave][0];
#pragma unroll
    for (int qs = 0; qs < 4; ++qs) {
#pragma unroll
      for (int kc = 0; kc < 4; ++kc) {
        f32x4 sacc = (f32x4){0.f, 0.f, 0.f, 0.f};
        sacc = __builtin_amdgcn_mfma_f32_16x16x32_bf16(aq[qs][0], bk[kc][0], sacc, 0, 0, 0);
        sacc = __builtin_amdgcn_mfma_f32_16x16x32_bf16(aq[qs][1], bk[kc][1], sacc, 0, 0, 0);
#pragma unroll
        for (int r = 0; r < 4; ++r) {
          float e = exp2f(sacc[r]);        // theta carries log2(e)
          myP[(quad * 4 + r) * LDK + kc * 16 + l15] =
              (unsigned short)(__builtin_bit_cast(unsigned int, e) >> 16);  // trunc bf16
        }
      }
      // consume P immediately (in-order per-wave LDS; verified pattern)
#pragma unroll
      for (int ks = 0; ks < 2; ++ks) {
        s16x8 ap = *(const s16x8*)(&myP[l15 * LDK + ks * 32 + quad * 8]);
        lacc[qs] = __builtin_amdgcn_mfma_f32_16x16x32_bf16(ap, bones, lacc[qs], 0, 0, 0);
#pragma unroll
        for (int ds = 0; ds < 4; ++ds)
          Oacc[qs][ds] = __builtin_amdgcn_mfma_f32_16x16x32_bf16(ap, bv[ks][ds], Oacc[qs][ds], 0, 0, 0);
      }
    }
  }

  // unnormalized partials out (bf16 O, fp32 l)
  unsigned short* Ob = Opart + (((size_t)seg * NB + b) * NSP + q0) * ICH;
#pragma unroll
  for (int qs = 0; qs < 4; ++qs)
#pragma unroll
    for (int ds = 0; ds < 4; ++ds)
#pragma unroll
      for (int r = 0; r < 4; ++r)
        Ob[(qs * 16 + quad * 4 + r) * ICH + ds * 16 + l15] = f2bf(Oacc[qs][ds][r]);
  if (l15 == 0) {
    float* lb = lpart + ((size_t)seg * NB + b) * NSP + q0;
#pragma unroll
    for (int qs = 0; qs < 4; ++qs)
#pragma unroll
      for (int r = 0; r < 4; ++r)
        lb[qs * 16 + quad * 4 + r] = lacc[qs][r];
  }
}

// ---------------- Kernel 3a: combine partials + W-proj + stats ---------------
// block: 4 waves, 64 n rows; wave: 16 n rows x all 128 co
__global__ __launch_bounds__(256) void k_wy(
    const unsigned short* __restrict__ Opart, const float* __restrict__ lpart,
    const float* __restrict__ Ww,
    float* __restrict__ WyT, float* __restrict__ stat)
{
  const int b = blockIdx.y, nt = blockIdx.x;   // nt 0..63
  const int t = threadIdx.x;
  const int wave = t >> 6, lane = t & 63;
  const int l15 = lane & 15, quad = lane >> 4;
  const int n0 = nt * 64 + wave * 16;
  // softmax denominator for row n0+l15
  float ls = 0.f;
#pragma unroll
  for (int s = 0; s < KSPLIT; ++s)
    ls += lpart[((size_t)s * NB + b) * NSP + n0 + l15];
  float inv = 1.0f / ls;
  // combine O partials -> y A-frags
  s16x8 ay[2];
#pragma unroll
  for (int ks = 0; ks < 2; ++ks) {
    float acc8[8];
#pragma unroll
    for (int j = 0; j < 8; ++j) acc8[j] = 0.f;
#pragma unroll
    for (int s = 0; s < KSPLIT; ++s) {
      const unsigned short* op =
          Opart + (((size_t)s * NB + b) * NSP + n0 + l15) * ICH + ks * 32 + quad * 8;
      u32x4 raw = *(const u32x4*)op;
#pragma unroll
      for (int w2 = 0; w2 < 4; ++w2) {
        unsigned int u = raw[w2];
        acc8[2 * w2]     += __builtin_bit_cast(float, u << 16);
        acc8[2 * w2 + 1] += __builtin_bit_cast(float, u & 0xFFFF0000u);
      }
    }
#pragma unroll
    for (int j = 0; j < 8; ++j) ay[ks][j] = (short)f2bf(acc8[j] * inv);
  }
  // Ww B-frags
  s16x8 bw[8][2];
#pragma unroll
  for (int cc = 0; cc < 8; ++cc)
#pragma unroll
    for (int ks = 0; ks < 2; ++ks) {
      const float* wp = Ww + (cc * 16 + l15) * ICH + ks * 32 + quad * 8;
      s16x8 e;
#pragma unroll
      for (int j = 0; j < 8; ++j) e[j] = (short)f2bf(wp[j]);
      bw[cc][ks] = e;
    }
  float sums[8], sq[8];
#pragma unroll
  for (int cc = 0; cc < 8; ++cc) { sums[cc] = 0.f; sq[cc] = 0.f; }
#pragma unroll
  for (int cc = 0; cc < 8; ++cc) {
    f32x4 acc = (f32x4){0.f, 0.f, 0.f, 0.f};
    acc = __builtin_amdgcn_mfma_f32_16x16x32_bf16(ay[0], bw[cc][0], acc, 0, 0, 0);
    acc = __builtin_amdgcn_mfma_f32_16x16x32_bf16(ay[1], bw[cc][1], acc, 0, 0, 0);
    float* wout = WyT + ((size_t)b * NSP + n0 + quad * 4) * CH + cc * 16 + l15;
#pragma unroll
    for (int r = 0; r < 4; ++r) {
      float v = acc[r];
      sums[cc] += v;
      sq[cc] += v * v;
      wout[r * CH] = v;
    }
  }
#pragma unroll
  for (int cc = 0; cc < 8; ++cc) {
    sums[cc] += __shfl_xor(sums[cc], 16, 64);
    sums[cc] += __shfl_xor(sums[cc], 32, 64);
    sq[cc] += __shfl_xor(sq[cc], 16, 64);
    sq[cc] += __shfl_xor(sq[cc], 32, 64);
  }
  if (quad == 0) {
#pragma unroll
    for (int cc = 0; cc < 8; ++cc) {
      atomicAdd(&stat[(b * CH + cc * 16 + l15) * 2 + 0], sums[cc]);
      atomicAdd(&stat[(b * CH + cc * 16 + l15) * 2 + 1], sq[cc]);
    }
  }
}

// ---------------- Kernel 3b: InstanceNorm + residual, out [B][C][N] ---------
__global__ __launch_bounds__(256) void k_norm(
    const float* __restrict__ WyT, const float* __restrict__ stat,
    const float* __restrict__ x, float* __restrict__ out)
{
  __shared__ float sWy[32 * 132];
  const int nt = blockIdx.x;        // 0..127
  const int b = blockIdx.y;
  const int t = threadIdx.x;
  const int n0 = nt * 32;
#pragma unroll
  for (int i = 0; i < 4; ++i) {
    int idx = t + 256 * i;
    int row = idx >> 5, c4 = idx & 31;
    *(float4*)(&sWy[row * 132 + c4 * 4]) =
        *(const float4*)(WyT + ((size_t)b * NSP + n0 + row) * CH + c4 * 4);
  }
  __syncthreads();
#pragma unroll
  for (int j = 0; j < 4; ++j) {
    int u = t + 256 * j;
    int co = u >> 3, nq = u & 7;
    float s = stat[(b * CH + co) * 2 + 0];
    float ss = stat[(b * CH + co) * 2 + 1];
    float mean = s * (1.f / NSP);
    float var = ss * (1.f / NSP) - mean * mean;
    float rs = rsqrtf(var + 1e-5f);
    float4 xv = *(const float4*)(x + (size_t)(b * CH + co) * NSP + n0 + nq * 4);
    float4 ov;
    ov.x = xv.x + (sWy[(nq * 4 + 0) * 132 + co] - mean) * rs;
    ov.y = xv.y + (sWy[(nq * 4 + 1) * 132 + co] - mean) * rs;
    ov.z = xv.z + (sWy[(nq * 4 + 2) * 132 + co] - mean) * rs;
    ov.w = xv.w + (sWy[(nq * 4 + 3) * 132 + co] - mean) * rs;
    *(float4*)(out + (size_t)(b * CH + co) * NSP + n0 + nq * 4) = ov;
  }
}

extern "C" void kernel_launch(void* const* d_in, const int* in_sizes, int n_in,
                              void* d_out, int out_size, void* d_ws, size_t ws_size,
                              hipStream_t stream)
{
  const float* x  = (const float*)d_in[0];
  const float* gw = (const float*)d_in[1];
  const float* gb = (const float*)d_in[2];
  const float* tw = (const float*)d_in[3];
  const float* tb = (const float*)d_in[4];
  const float* pw = (const float*)d_in[5];
  const float* pb = (const float*)d_in[6];
  const float* Ww = (const float*)d_in[7];
  // d_in[8] = W_b: canceled by InstanceNorm -> unused
  float* out = (float*)d_out;
  char* ws = (char*)d_ws;
  // workspace layout (~49.3 MB)
  unsigned short* thetaT = (unsigned short*)(ws);                        // 2 MB
  unsigned short* phiT   = (unsigned short*)(ws + (2ull << 20));         // 2 MB
  unsigned short* gmat   = (unsigned short*)(ws + (4ull << 20));         // 2 MB
  float* WyT   = (float*)(ws + (8ull << 20));                            // 8 MB
  float* stat  = (float*)(ws + (16ull << 20));                           // 4 KB
  float* lpart = (float*)(ws + (16ull << 20) + (1ull << 18));            // 1 MB
  unsigned short* Opart = (unsigned short*)(ws + (17ull << 20) + (1ull << 18)); // 32 MB

  hipMemsetAsync(stat, 0, NB * CH * 2 * sizeof(float), stream);
  k_proj<<<dim3(64, 4, 3), 256, 0, stream>>>(x, gw, gb, tw, tb, pw, pb, thetaT, phiT, gmat);
  k_attn<<<dim3(16, 4, KSPLIT), 256, 0, stream>>>(thetaT, phiT, gmat, Opart, lpart);
  k_wy<<<dim3(64, 4), 256, 0, stream>>>(Opart, lpart, Ww, WyT, stat);
  k_norm<<<dim3(128, 4), 256, 0, stream>>>(WyT, stat, x, out);
}